// Round 7
// baseline (182.437 us; speedup 1.0000x reference)
//
#include <hip/hip_runtime.h>
#include <math.h>

// Problem constants
#define NRAYS        32768
#define MARCH_ITERS  64
#define EPS_         1e-4f
#define STEP_        ((1.0f + 1.0f/64.0f) / 64.0f)   // exact in fp32

typedef __attribute__((ext_vector_type(8)))  short    short8;   // 8 bf16
typedef __attribute__((ext_vector_type(4)))  float    float4v;  // C/D frag
typedef __attribute__((ext_vector_type(2)))  float    float2v;  // pk-f32 pair
typedef __attribute__((ext_vector_type(4)))  unsigned uint4v;

__device__ __forceinline__ short8 mk_frag(unsigned p0, unsigned p1,
                                          unsigned p2, unsigned p3) {
    uint4v v = {p0, p1, p2, p3};
    return __builtin_bit_cast(short8, v);
}

// One v_perm_b32: low16 = trunc-bf16(a), high16 = trunc-bf16(b).
__device__ __forceinline__ unsigned packbf(unsigned a, unsigned b) {
    return __builtin_amdgcn_perm(b, a, 0x07060302u);
}

// 2-way split: hi + residual (packbf of r truncates -> the mid limb).
struct Split2 { unsigned h, r; };
__device__ __forceinline__ Split2 split2(float x) {
    unsigned xu = __float_as_uint(x);
    float xh = __uint_as_float(xu & 0xFFFF0000u);
    float rr = x - xh;                        // exact residual
    return { xu, __float_as_uint(rr) };
}

// packed f32 fma -> v_pk_fma_f32 (lane-exact == 2 scalar v_fma_f32)
__device__ __forceinline__ float2v fma2(float2v a, float2v b, float2v c) {
    return __builtin_elementwise_fma(a, b, c);
}

// R21: vector-ISSUE reduction. R15/R18/R19/R20 all ~127-139us with
// VALUBusy+MfmaUtil = 103/91/93/98% -- the per-SIMD vector issue stream
// (shared by VALU and MFMA) is saturated in every configuration; no
// restructuring of residency/ILP/storage moved it. Only fewer issue
// cycles per eval helps. Three cuts:
// (1) LINEAR-L1: eval point p = o + c*d is affine in scalar c, so
//     L1 pre-act = a + c*s with a = W0^T o + b0, s = W0^T d precomputed
//     per-lane (hidden j = H(t,q,r) = 32*(t>>1)+8q+4*(t&1)+r, the SAME
//     assignment the old C1 produced, so the repack->B2 in-lane mapping
//     is untouched). Kills per eval: 4 MFMAs (64 cyc of the saturated
//     pipe) + buildB1 (12) + pos fmaf (3); adds 8 v_pk_fma_f32.
// (2) b1 as the first C2 MFMA's C-input (D != C is legal): kills the
//     16 v_mov C2-init per eval. Bit-identical accumulation order.
// (3) pk-f32 for residual subs and l3 fmafs (v_pk_*_f32 is lane-exact;
//     summation tree preserved) -> bit-identical, ~24 fewer insts/eval.
// L2 limb products, MFMA order, l3 reduction order: UNCHANGED.
// Numerics: only L1 activations shift by O(ulp) (fmaf regrouping);
// expected absmax 0.00390625 as before.
// 4096 single-wave blocks (even=march, odd=tput), zero LDS;
// waves_per_eu(2,8): 256-reg budget, no spill incentive (issue-bound ->
// residency is second-order; avoid spill at all costs).
// MFMA layouts (R6-verified): A[row=lane&15][k=quad*8+j],
// B[k=quad*8+j][col=lane&15], C/D col=lane&15 row=quad*4+reg.
// Precision: march L2 = 3 products (m,h)(h,m)(h,h); tput L2 = 2 products.
__global__ __launch_bounds__(64)
__attribute__((amdgpu_waves_per_eu(2, 8)))
void sdf_w10_k(
    const float* __restrict__ rays,
    const float* __restrict__ W0,  const float* __restrict__ b0,
    const float* __restrict__ W1,  const float* __restrict__ b1,
    const float* __restrict__ W2,  const float* __restrict__ b2,
    const float* __restrict__ Wr0, const float* __restrict__ br0,
    const float* __restrict__ Wr1, const float* __restrict__ br1,
    float* __restrict__ out)
{
    const int lane = threadIdx.x;             // 0..63, one wave per block
    const int kind = blockIdx.x & 1;          // 0 = march, 1 = tput
    const int quad = lane >> 4;
    const int m    = lane & 15;
    const int rayBase = (blockIdx.x >> 1) * 16;

    // ---- per-lane ray (ray = rayBase + m, replicated over quads) ----
    const float* rp = rays + (rayBase + m) * 6;
    const float ox = rp[0], oy = rp[1], oz = rp[2];
    const float dx = rp[3], dy = rp[4], dz = rp[5];

    // ---- linear-L1 coefficients: hidden j = H(t,q,r), value index r=2p+e.
    // a = W0^T o + b0, s = W0^T d; per-eval L1 = relu(a + c*s).
    float2v a2[4][2], s2[4][2];
    #pragma unroll
    for (int t = 0; t < 4; ++t)
        #pragma unroll
        for (int p = 0; p < 2; ++p) {
            float av[2], sv[2];
            #pragma unroll
            for (int e = 0; e < 2; ++e) {
                int j = 32 * (t >> 1) + 8 * quad + 4 * (t & 1) + (2 * p + e);
                float w0c = W0[j], w1c = W0[64 + j], w2c = W0[128 + j];
                av[e] = fmaf(ox, w0c, fmaf(oy, w1c, fmaf(oz, w2c, b0[j])));
                sv[e] = fmaf(dx, w0c, fmaf(dy, w1c, dz * w2c));
            }
            a2[t][p] = (float2v){av[0], av[1]};
            s2[t][p] = (float2v){sv[0], sv[1]};
        }

    // ---- b1 (first-product C-input) and W2 (L3), rows j2 = 16t+4q+r ----
    float4v b1v[4];
    float2v w2a[4], w2b[4];
    #pragma unroll
    for (int t = 0; t < 4; ++t) {
        int base = 16 * t + 4 * quad;
        b1v[t] = (float4v){b1[base], b1[base + 1], b1[base + 2], b1[base + 3]};
        w2a[t] = (float2v){W2[base], W2[base + 1]};
        w2b[t] = (float2v){W2[base + 2], W2[base + 3]};
    }
    const float b2s = b2[0];

    // ---- shared front-end: c -> L1 = relu(a + c*s) -> split2 pack ----
    auto front = [&](float cv, short8* BH, short8* BM) {
        const float2v c2 = {cv, cv};
        unsigned PH[4][2], PM[4][2];
        #pragma unroll
        for (int t = 0; t < 4; ++t) {
            float2v v01 = fma2(c2, s2[t][0], a2[t][0]);
            float2v v23 = fma2(c2, s2[t][1], a2[t][1]);
            float v0 = fmaxf(v01.x, 0.f), v1 = fmaxf(v01.y, 0.f);
            float v2 = fmaxf(v23.x, 0.f), v3 = fmaxf(v23.y, 0.f);
            unsigned u0 = __float_as_uint(v0), u1 = __float_as_uint(v1);
            unsigned u2 = __float_as_uint(v2), u3 = __float_as_uint(v3);
            PH[t][0] = packbf(u0, u1); PH[t][1] = packbf(u2, u3);
            float2v h01 = {__uint_as_float(u0 & 0xFFFF0000u),
                           __uint_as_float(u1 & 0xFFFF0000u)};
            float2v h23 = {__uint_as_float(u2 & 0xFFFF0000u),
                           __uint_as_float(u3 & 0xFFFF0000u)};
            float2v r01 = (float2v){v0, v1} - h01;   // pk sub, exact residual
            float2v r23 = (float2v){v2, v3} - h23;
            PM[t][0] = packbf(__float_as_uint(r01.x), __float_as_uint(r01.y));
            PM[t][1] = packbf(__float_as_uint(r23.x), __float_as_uint(r23.y));
        }
        #pragma unroll
        for (int h = 0; h < 2; ++h) {
            BH[h] = mk_frag(PH[2 * h][0], PH[2 * h][1],
                            PH[2 * h + 1][0], PH[2 * h + 1][1]);
            BM[h] = mk_frag(PM[2 * h][0], PM[2 * h][1],
                            PM[2 * h + 1][0], PM[2 * h + 1][1]);
        }
    };

    // ---- L3: in-lane relu*W2 (pk fma), 2 cross-quad shuffles ----
    auto l3 = [&](const float4v* C2) -> float {
        float2v q01 = {0.f, 0.f}, q23 = {0.f, 0.f};
        #pragma unroll
        for (int t = 0; t < 4; ++t) {
            float2v rel01 = {fmaxf(C2[t][0], 0.f), fmaxf(C2[t][1], 0.f)};
            float2v rel23 = {fmaxf(C2[t][2], 0.f), fmaxf(C2[t][3], 0.f)};
            q01 = fma2(rel01, w2a[t], q01);
            q23 = fma2(rel23, w2b[t], q23);
        }
        float part = (q01.x + q01.y) + (q23.x + q23.y);
        part += __shfl_xor(part, 16, 64);
        part += __shfl_xor(part, 32, 64);
        return b2s + part;
    };

    if (kind == 0) {
        // =================== MARCH block: 64 sequential evals ==============
        // Both W1 limb sets live in registers: A2h (hi) + A2m (mid), 64 regs.
        short8 A2h[2][4], A2m[2][4];
        #pragma unroll
        for (int h = 0; h < 2; ++h)
            #pragma unroll
            for (int t = 0; t < 4; ++t) {
                unsigned pm[4], ph[4];
                #pragma unroll
                for (int jp = 0; jp < 4; ++jp) {
                    int k0 = 32 * h + quad * 8 + 2 * jp;
                    int j2 = 16 * t + m;
                    Split2 a = split2(W1[k0 * 64 + j2]);
                    Split2 b = split2(W1[(k0 + 1) * 64 + j2]);
                    pm[jp] = packbf(a.r, b.r);   // trunc(residual) == mid limb
                    ph[jp] = packbf(a.h, b.h);   // trunc(full) == hi limb
                }
                A2m[h][t] = mk_frag(pm[0], pm[1], pm[2], pm[3]);
                A2h[h][t] = mk_frag(ph[0], ph[1], ph[2], ph[3]);
            }

        bool  hit = false;
        float cd  = 0.f;
        #pragma unroll 1
        for (int it = 0; it < MARCH_ITERS; ++it) {
            if (__all(hit)) break;
            short8 BH[2], BM[2];
            front(cd, BH, BM);
            // L2: 3 products, small first: (m,h)(h,m)(h,h); 24 MFMAs.
            // First product reads b1v as C-input (no C2 init movs).
            // Accumulation order identical to R20 -> bit-identical L2.
            float4v C2[4];
            #pragma unroll
            for (int t = 0; t < 4; ++t)
                C2[t] = __builtin_amdgcn_mfma_f32_16x16x32_bf16(
                    A2m[0][t], BH[0], b1v[t], 0, 0, 0);
            #pragma unroll
            for (int t = 0; t < 4; ++t)
                C2[t] = __builtin_amdgcn_mfma_f32_16x16x32_bf16(
                    A2m[1][t], BH[1], C2[t], 0, 0, 0);
            #pragma unroll
            for (int h = 0; h < 2; ++h)
                #pragma unroll
                for (int t = 0; t < 4; ++t)
                    C2[t] = __builtin_amdgcn_mfma_f32_16x16x32_bf16(
                        A2h[h][t], BM[h], C2[t], 0, 0, 0);
            #pragma unroll
            for (int h = 0; h < 2; ++h)
                #pragma unroll
                for (int t = 0; t < 4; ++t)
                    C2[t] = __builtin_amdgcn_mfma_f32_16x16x32_bf16(
                        A2h[h][t], BH[h], C2[t], 0, 0, 0);
            float dm = l3(C2);
            bool c = (dm < EPS_) && (cd >= 0.f) && (cd <= 1.f);
            hit = hit || c;
            if (!hit) cd += dm;
        }

        // ---- reflection net: quad q handles hidden j in [16q, 16q+16) ----
        const float px = fmaf(dx, cd, ox), py = fmaf(dy, cd, oy), pz = fmaf(dz, cd, oz);
        float r0 = 0.f, r1 = 0.f, r2 = 0.f;
        #pragma unroll 4
        for (int jj = 0; jj < 16; ++jj) {
            int j = quad * 16 + jj;
            float a = fmaf(px, Wr0[j],
                      fmaf(py, Wr0[64 + j],
                      fmaf(pz, Wr0[128 + j],
                      fmaf(dx, Wr0[192 + j],
                      fmaf(dy, Wr0[256 + j],
                      fmaf(dz, Wr0[320 + j], br0[j]))))));
            a = fmaxf(a, 0.f);
            r0 = fmaf(a, Wr1[j * 3 + 0], r0);
            r1 = fmaf(a, Wr1[j * 3 + 1], r1);
            r2 = fmaf(a, Wr1[j * 3 + 2], r2);
        }
        r0 += __shfl_xor(r0, 16, 64); r0 += __shfl_xor(r0, 32, 64);
        r1 += __shfl_xor(r1, 16, 64); r1 += __shfl_xor(r1, 32, 64);
        r2 += __shfl_xor(r2, 16, 64); r2 += __shfl_xor(r2, 32, 64);
        r0 = 1.f / (1.f + expf(-(r0 + br1[0])));
        r1 = 1.f / (1.f + expf(-(r1 + br1[1])));
        r2 = 1.f / (1.f + expf(-(r2 + br1[2])));
        if (!hit) { r0 = 0.f; r1 = 0.f; r2 = 0.f; }
        if (lane < 16) {
            float* op = out + (rayBase + lane) * 4;
            op[0] = r0; op[1] = r1; op[2] = r2;
        }
    } else {
        // =================== TPUT block: 65 independent evals ==============
        // Only the hi limbs needed (2-product L2): A2h in 32 registers.
        short8 A2h[2][4];
        #pragma unroll
        for (int h = 0; h < 2; ++h)
            #pragma unroll
            for (int t = 0; t < 4; ++t) {
                unsigned ph[4];
                #pragma unroll
                for (int jp = 0; jp < 4; ++jp) {
                    int k0 = 32 * h + quad * 8 + 2 * jp;
                    int j2 = 16 * t + m;
                    ph[jp] = packbf(__float_as_uint(W1[k0 * 64 + j2]),
                                    __float_as_uint(W1[(k0 + 1) * 64 + j2]));
                }
                A2h[h][t] = mk_frag(ph[0], ph[1], ph[2], ph[3]);
            }

        // i=0 at origin (== reference curr_min0), then t = STEP*i. unroll-1.
        float cm = 3.4e38f;
        #pragma unroll 1
        for (int i = 0; i <= 64; ++i) {
            float ti = STEP_ * (float)i;
            short8 BH[2], BM[2];
            front(ti, BH, BM);
            // L2: 2 products (h,m)(h,h); 16 MFMAs; b1 folded into first.
            float4v C2[4];
            #pragma unroll
            for (int t = 0; t < 4; ++t)
                C2[t] = __builtin_amdgcn_mfma_f32_16x16x32_bf16(
                    A2h[0][t], BM[0], b1v[t], 0, 0, 0);
            #pragma unroll
            for (int t = 0; t < 4; ++t)
                C2[t] = __builtin_amdgcn_mfma_f32_16x16x32_bf16(
                    A2h[1][t], BM[1], C2[t], 0, 0, 0);
            #pragma unroll
            for (int h = 0; h < 2; ++h)
                #pragma unroll
                for (int t = 0; t < 4; ++t)
                    C2[t] = __builtin_amdgcn_mfma_f32_16x16x32_bf16(
                        A2h[h][t], BH[h], C2[t], 0, 0, 0);
            float dt = l3(C2);
            cm = fminf(cm, dt);
        }
        if (lane < 16)
            out[(rayBase + lane) * 4 + 3] = cm;
    }
}

extern "C" void kernel_launch(void* const* d_in, const int* in_sizes, int n_in,
                              void* d_out, int out_size, void* d_ws, size_t ws_size,
                              hipStream_t stream) {
    const float* rays = (const float*)d_in[0];
    const float* W0   = (const float*)d_in[1];
    const float* b0   = (const float*)d_in[2];
    const float* W1   = (const float*)d_in[3];
    const float* b1   = (const float*)d_in[4];
    const float* W2   = (const float*)d_in[5];
    const float* b2   = (const float*)d_in[6];
    const float* Wr0  = (const float*)d_in[7];
    const float* br0  = (const float*)d_in[8];
    const float* Wr1  = (const float*)d_in[9];
    const float* br1  = (const float*)d_in[10];
    float* out = (float*)d_out;

    // 4096 single-wave blocks: even = march, odd = tput, 16 rays each.
    // Zero LDS; weights + linear-L1 coefficients register-resident.
    // Issue-bound: the win is fewer insts/eval (no C1 MFMAs, no C2-init
    // movs, pk-f32 packing), not occupancy.
    hipLaunchKernelGGL(sdf_w10_k, dim3((NRAYS / 16) * 2), dim3(64), 0, stream,
                       rays, W0, b0, W1, b1, W2, b2, Wr0, br0, Wr1, br1, out);
}

// Round 8
// 167.852 us; speedup vs baseline: 1.0869x; 1.0869x over previous
//
#include <hip/hip_runtime.h>
#include <math.h>

// Problem constants
#define NRAYS        32768
#define MARCH_ITERS  64
#define EPS_         1e-4f
#define STEP_        ((1.0f + 1.0f/64.0f) / 64.0f)   // exact in fp32

typedef __attribute__((ext_vector_type(8)))  short    short8;   // 8 bf16
typedef __attribute__((ext_vector_type(4)))  float    float4v;  // C/D frag
typedef __attribute__((ext_vector_type(2)))  float    float2v;  // pk-f32 pair
typedef __attribute__((ext_vector_type(4)))  unsigned uint4v;

__device__ __forceinline__ short8 mk_frag(unsigned p0, unsigned p1,
                                          unsigned p2, unsigned p3) {
    uint4v v = {p0, p1, p2, p3};
    return __builtin_bit_cast(short8, v);
}

// One v_perm_b32: low16 = trunc-bf16(a), high16 = trunc-bf16(b).
__device__ __forceinline__ unsigned packbf(unsigned a, unsigned b) {
    return __builtin_amdgcn_perm(b, a, 0x07060302u);
}

// 2-way split: hi + residual (packbf of r truncates -> the mid limb).
struct Split2 { unsigned h, r; };
__device__ __forceinline__ Split2 split2(float x) {
    unsigned xu = __float_as_uint(x);
    float xh = __uint_as_float(xu & 0xFFFF0000u);
    float rr = x - xh;                        // exact residual
    return { xu, __float_as_uint(rr) };
}

// packed f32 fma -> v_pk_fma_f32 (lane-exact == 2 scalar v_fma_f32)
__device__ __forceinline__ float2v fma2(float2v a, float2v b, float2v c) {
    return __builtin_elementwise_fma(a, b, c);
}

// R22: FUSED march+tput in one wave -- in-order-issue stall filling.
// R21 post-mortem killed the issue-bound theory: cutting 19% of both
// pipes' work (verified via util x dur) moved dur only -1.5%; both utils
// DROPPED. Closing model: per-SIMD 16x16x32 MFMA throughput ~19.4 cyc
// (m06 ceiling / 1024 SIMDs) -> total matrix work = 100k cyc/SIMD = 42us
// = measured MfmaUtil (32% of 312k cyc) and = FLOP check (674 TF = 32%
// of 2075 TF ceiling). The other ~87us is per-wave IN-ORDER stall: each
// wave's stream is a serial chain (front -> 6 dep MFMA stages -> l3 with
// 2 x ~120cyc ds_bpermute shuffles -> cd -> next front); when the next
// instruction waits, the wave stalls even though independent work exists
// later in its own stream. 2-4 identical waves/SIMD don't cover it.
// Fix: the tput stream (65 INDEPENDENT evals) is guaranteed-ready filler
// for the march chain. One wave per 16 rays runs both, interleaved per
// iteration: front_t; front_m; MFMA_m; MFMA_t; l3_m; update; l3_t --
// every serial march dependency has 40-60 independent tput instructions
// between producer and consumer. All-hit -> tput-only remainder loop
// (march semantics unchanged). Per-stream arithmetic is bit-identical to
// R21 -> absmax must stay 0.00390625. rgb+cm now one float4 store.
// 2048 blocks x 64 threads = 2 waves/SIMD; waves_per_eu(2,8): 256-reg
// budget (demand ~210; WRITE_SIZE is the spill tripwire).
// MFMA layouts (R6-verified): A[row=lane&15][k=quad*8+j],
// B[k=quad*8+j][col=lane&15], C/D col=lane&15 row=quad*4+reg.
// Precision: march L2 = 3 products (m,h)(h,m)(h,h); tput L2 = 2 products.
__global__ __launch_bounds__(64)
__attribute__((amdgpu_waves_per_eu(2, 8)))
void sdf_w11_k(
    const float* __restrict__ rays,
    const float* __restrict__ W0,  const float* __restrict__ b0,
    const float* __restrict__ W1,  const float* __restrict__ b1,
    const float* __restrict__ W2,  const float* __restrict__ b2,
    const float* __restrict__ Wr0, const float* __restrict__ br0,
    const float* __restrict__ Wr1, const float* __restrict__ br1,
    float* __restrict__ out)
{
    const int lane = threadIdx.x;             // 0..63, one wave per block
    const int quad = lane >> 4;
    const int m    = lane & 15;
    const int rayBase = blockIdx.x * 16;

    // ---- per-lane ray (ray = rayBase + m, replicated over quads) ----
    const float* rp = rays + (rayBase + m) * 6;
    const float ox = rp[0], oy = rp[1], oz = rp[2];
    const float dx = rp[3], dy = rp[4], dz = rp[5];

    // ---- linear-L1 coefficients (R21): L1 pre-act = a + c*s ----
    float2v a2[4][2], s2[4][2];
    #pragma unroll
    for (int t = 0; t < 4; ++t)
        #pragma unroll
        for (int p = 0; p < 2; ++p) {
            float av[2], sv[2];
            #pragma unroll
            for (int e = 0; e < 2; ++e) {
                int j = 32 * (t >> 1) + 8 * quad + 4 * (t & 1) + (2 * p + e);
                float w0c = W0[j], w1c = W0[64 + j], w2c = W0[128 + j];
                av[e] = fmaf(ox, w0c, fmaf(oy, w1c, fmaf(oz, w2c, b0[j])));
                sv[e] = fmaf(dx, w0c, fmaf(dy, w1c, dz * w2c));
            }
            a2[t][p] = (float2v){av[0], av[1]};
            s2[t][p] = (float2v){sv[0], sv[1]};
        }

    // ---- b1 (first-product C-input) and W2 (L3), rows j2 = 16t+4q+r ----
    float4v b1v[4];
    float2v w2a[4], w2b[4];
    #pragma unroll
    for (int t = 0; t < 4; ++t) {
        int base = 16 * t + 4 * quad;
        b1v[t] = (float4v){b1[base], b1[base + 1], b1[base + 2], b1[base + 3]};
        w2a[t] = (float2v){W2[base], W2[base + 1]};
        w2b[t] = (float2v){W2[base + 2], W2[base + 3]};
    }
    const float b2s = b2[0];

    // ---- W1 limbs: A2h (hi) + A2m (mid), 64 regs, shared by streams ----
    short8 A2h[2][4], A2m[2][4];
    #pragma unroll
    for (int h = 0; h < 2; ++h)
        #pragma unroll
        for (int t = 0; t < 4; ++t) {
            unsigned pm[4], ph[4];
            #pragma unroll
            for (int jp = 0; jp < 4; ++jp) {
                int k0 = 32 * h + quad * 8 + 2 * jp;
                int j2 = 16 * t + m;
                Split2 a = split2(W1[k0 * 64 + j2]);
                Split2 b = split2(W1[(k0 + 1) * 64 + j2]);
                pm[jp] = packbf(a.r, b.r);   // trunc(residual) == mid limb
                ph[jp] = packbf(a.h, b.h);   // trunc(full) == hi limb
            }
            A2m[h][t] = mk_frag(pm[0], pm[1], pm[2], pm[3]);
            A2h[h][t] = mk_frag(ph[0], ph[1], ph[2], ph[3]);
        }

    // ---- shared front-end: c -> L1 = relu(a + c*s) -> split2 pack ----
    auto front = [&](float cv, short8* BH, short8* BM) {
        const float2v c2 = {cv, cv};
        unsigned PH[4][2], PM[4][2];
        #pragma unroll
        for (int t = 0; t < 4; ++t) {
            float2v v01 = fma2(c2, s2[t][0], a2[t][0]);
            float2v v23 = fma2(c2, s2[t][1], a2[t][1]);
            float v0 = fmaxf(v01.x, 0.f), v1 = fmaxf(v01.y, 0.f);
            float v2 = fmaxf(v23.x, 0.f), v3 = fmaxf(v23.y, 0.f);
            unsigned u0 = __float_as_uint(v0), u1 = __float_as_uint(v1);
            unsigned u2 = __float_as_uint(v2), u3 = __float_as_uint(v3);
            PH[t][0] = packbf(u0, u1); PH[t][1] = packbf(u2, u3);
            float2v h01 = {__uint_as_float(u0 & 0xFFFF0000u),
                           __uint_as_float(u1 & 0xFFFF0000u)};
            float2v h23 = {__uint_as_float(u2 & 0xFFFF0000u),
                           __uint_as_float(u3 & 0xFFFF0000u)};
            float2v r01 = (float2v){v0, v1} - h01;   // pk sub, exact residual
            float2v r23 = (float2v){v2, v3} - h23;
            PM[t][0] = packbf(__float_as_uint(r01.x), __float_as_uint(r01.y));
            PM[t][1] = packbf(__float_as_uint(r23.x), __float_as_uint(r23.y));
        }
        #pragma unroll
        for (int h = 0; h < 2; ++h) {
            BH[h] = mk_frag(PH[2 * h][0], PH[2 * h][1],
                            PH[2 * h + 1][0], PH[2 * h + 1][1]);
            BM[h] = mk_frag(PM[2 * h][0], PM[2 * h][1],
                            PM[2 * h + 1][0], PM[2 * h + 1][1]);
        }
    };

    // ---- L3: in-lane relu*W2 (pk fma), 2 cross-quad shuffles ----
    auto l3 = [&](const float4v* C2) -> float {
        float2v q01 = {0.f, 0.f}, q23 = {0.f, 0.f};
        #pragma unroll
        for (int t = 0; t < 4; ++t) {
            float2v rel01 = {fmaxf(C2[t][0], 0.f), fmaxf(C2[t][1], 0.f)};
            float2v rel23 = {fmaxf(C2[t][2], 0.f), fmaxf(C2[t][3], 0.f)};
            q01 = fma2(rel01, w2a[t], q01);
            q23 = fma2(rel23, w2b[t], q23);
        }
        float part = (q01.x + q01.y) + (q23.x + q23.y);
        part += __shfl_xor(part, 16, 64);
        part += __shfl_xor(part, 32, 64);
        return b2s + part;
    };

    // tput L2: 2 products (h,m)(h,h), b1 folded into first. Same as R21.
    auto tputC2 = [&](const short8* BHt, const short8* BMt, float4v* C2t) {
        #pragma unroll
        for (int t = 0; t < 4; ++t)
            C2t[t] = __builtin_amdgcn_mfma_f32_16x16x32_bf16(
                A2h[0][t], BMt[0], b1v[t], 0, 0, 0);
        #pragma unroll
        for (int t = 0; t < 4; ++t)
            C2t[t] = __builtin_amdgcn_mfma_f32_16x16x32_bf16(
                A2h[1][t], BMt[1], C2t[t], 0, 0, 0);
        #pragma unroll
        for (int h = 0; h < 2; ++h)
            #pragma unroll
            for (int t = 0; t < 4; ++t)
                C2t[t] = __builtin_amdgcn_mfma_f32_16x16x32_bf16(
                    A2h[h][t], BHt[h], C2t[t], 0, 0, 0);
    };

    bool  hit = false;
    float cd  = 0.f;
    float cm  = 3.4e38f;
    int   i   = 0;

    // =========== FUSED loop: march iter i (i<64) + tput eval i ===========
    #pragma unroll 1
    for (; i <= 64; ++i) {
        if (i >= MARCH_ITERS || __all(hit)) break;   // -> tput-only remainder
        // 1) tput front first: independent work covering the backedge
        //    latency of the march chain (l3_m of iter i-1 -> cd -> front_m).
        float ti = STEP_ * (float)i;
        short8 BHt[2], BMt[2];
        front(ti, BHt, BMt);
        // 2) march front (needs cd)
        short8 BHm[2], BMm[2];
        front(cd, BHm, BMm);
        // 3) march MFMAs first (6 stages), so C2m is deep in the pipe
        //    before l3_m reads it; tput MFMAs (4 stages) issue meanwhile.
        float4v C2m[4], C2t[4];
        #pragma unroll
        for (int t = 0; t < 4; ++t)
            C2m[t] = __builtin_amdgcn_mfma_f32_16x16x32_bf16(
                A2m[0][t], BHm[0], b1v[t], 0, 0, 0);
        #pragma unroll
        for (int t = 0; t < 4; ++t)
            C2m[t] = __builtin_amdgcn_mfma_f32_16x16x32_bf16(
                A2m[1][t], BHm[1], C2m[t], 0, 0, 0);
        #pragma unroll
        for (int h = 0; h < 2; ++h)
            #pragma unroll
            for (int t = 0; t < 4; ++t)
                C2m[t] = __builtin_amdgcn_mfma_f32_16x16x32_bf16(
                    A2h[h][t], BMm[h], C2m[t], 0, 0, 0);
        #pragma unroll
        for (int h = 0; h < 2; ++h)
            #pragma unroll
            for (int t = 0; t < 4; ++t)
                C2m[t] = __builtin_amdgcn_mfma_f32_16x16x32_bf16(
                    A2h[h][t], BHm[h], C2m[t], 0, 0, 0);
        tputC2(BHt, BMt, C2t);
        // 4) march finish (serial chain) while tput MFMAs drain
        float dm = l3(C2m);
        bool c = (dm < EPS_) && (cd >= 0.f) && (cd <= 1.f);
        hit = hit || c;
        if (!hit) cd += dm;
        // 5) tput finish
        cm = fminf(cm, l3(C2t));
    }

    // =========== tput-only remainder (march done / all-hit) ==============
    #pragma unroll 1
    for (; i <= 64; ++i) {
        float ti = STEP_ * (float)i;
        short8 BHt[2], BMt[2];
        front(ti, BHt, BMt);
        float4v C2t[4];
        tputC2(BHt, BMt, C2t);
        cm = fminf(cm, l3(C2t));
    }

    // ---- reflection net: quad q handles hidden j in [16q, 16q+16) ----
    const float px = fmaf(dx, cd, ox), py = fmaf(dy, cd, oy), pz = fmaf(dz, cd, oz);
    float r0 = 0.f, r1 = 0.f, r2 = 0.f;
    #pragma unroll 4
    for (int jj = 0; jj < 16; ++jj) {
        int j = quad * 16 + jj;
        float a = fmaf(px, Wr0[j],
                  fmaf(py, Wr0[64 + j],
                  fmaf(pz, Wr0[128 + j],
                  fmaf(dx, Wr0[192 + j],
                  fmaf(dy, Wr0[256 + j],
                  fmaf(dz, Wr0[320 + j], br0[j]))))));
        a = fmaxf(a, 0.f);
        r0 = fmaf(a, Wr1[j * 3 + 0], r0);
        r1 = fmaf(a, Wr1[j * 3 + 1], r1);
        r2 = fmaf(a, Wr1[j * 3 + 2], r2);
    }
    r0 += __shfl_xor(r0, 16, 64); r0 += __shfl_xor(r0, 32, 64);
    r1 += __shfl_xor(r1, 16, 64); r1 += __shfl_xor(r1, 32, 64);
    r2 += __shfl_xor(r2, 16, 64); r2 += __shfl_xor(r2, 32, 64);
    r0 = 1.f / (1.f + expf(-(r0 + br1[0])));
    r1 = 1.f / (1.f + expf(-(r1 + br1[1])));
    r2 = 1.f / (1.f + expf(-(r2 + br1[2])));
    if (!hit) { r0 = 0.f; r1 = 0.f; r2 = 0.f; }
    if (lane < 16) {
        // one coalesced float4 store: rgb + tput
        float4v o4 = {r0, r1, r2, cm};
        *reinterpret_cast<float4v*>(out + (rayBase + lane) * 4) = o4;
    }
}

extern "C" void kernel_launch(void* const* d_in, const int* in_sizes, int n_in,
                              void* d_out, int out_size, void* d_ws, size_t ws_size,
                              hipStream_t stream) {
    const float* rays = (const float*)d_in[0];
    const float* W0   = (const float*)d_in[1];
    const float* b0   = (const float*)d_in[2];
    const float* W1   = (const float*)d_in[3];
    const float* b1   = (const float*)d_in[4];
    const float* W2   = (const float*)d_in[5];
    const float* b2   = (const float*)d_in[6];
    const float* Wr0  = (const float*)d_in[7];
    const float* br0  = (const float*)d_in[8];
    const float* Wr1  = (const float*)d_in[9];
    const float* br1  = (const float*)d_in[10];
    float* out = (float*)d_out;

    // 2048 single-wave blocks, 16 rays each, march+tput FUSED per wave:
    // the tput stream's independent evals fill the march chain's in-order
    // stall slots. Zero LDS; ~210 regs; waves_per_eu(2,8) -> 256 budget,
    // 2 waves/SIMD, all resident in one round.
    hipLaunchKernelGGL(sdf_w11_k, dim3(NRAYS / 16), dim3(64), 0, stream,
                       rays, W0, b0, W1, b1, W2, b2, Wr0, br0, Wr1, br1, out);
}